// Round 8
// baseline (211.221 us; speedup 1.0000x reference)
//
#include <hip/hip_runtime.h>
#include <math.h>

typedef __attribute__((ext_vector_type(8))) short bf16x8;
typedef __attribute__((ext_vector_type(4))) float f32x4;

__device__ __forceinline__ short f2b(float f) {
  union { float f; unsigned u; } v; v.f = f;
  unsigned u = v.u + 0x7fffu + ((v.u >> 16) & 1u);
  return (short)(u >> 16);
}

// pack two float4 (8 consecutive fp32) into one bf16x8 fragment
__device__ __forceinline__ bf16x8 cvt8(float4 a, float4 b) {
  bf16x8 r;
  r[0] = f2b(a.x); r[1] = f2b(a.y); r[2] = f2b(a.z); r[3] = f2b(a.w);
  r[4] = f2b(b.x); r[5] = f2b(b.y); r[6] = f2b(b.z); r[7] = f2b(b.w);
  return r;
}

// ---------------------------------------------------------------------------
// K1: enc1 (K=512) + LN + relu -> enc2 (K=256) -> mf bf16.
// 512 threads (8 waves x 2 n-frags), fp32 weights converted in-register,
// depth-4 global prefetch. Block 0 also zeroes poolctx.
// ---------------------------------------------------------------------------
__global__ __launch_bounds__(512) void k_enc(
    const float* __restrict__ me,
    const float* __restrict__ w1f, const float* __restrict__ b1,
    const float* __restrict__ g, const float* __restrict__ lb,
    const float* __restrict__ w2f, const float* __restrict__ b2,
    unsigned short* __restrict__ mfb, float* __restrict__ poolctx) {
  __shared__ float hh[16 * 260];
  __shared__ unsigned short rA[16 * 264];
  __shared__ unsigned short mfs[16 * 256];
  int tid = threadIdx.x, lane = tid & 63, w = tid >> 6;  // w in [0,8)
  int row0 = blockIdx.x * 16;
  int m = lane & 15, q = lane >> 4;
  if (blockIdx.x == 0) {
    float4 z = {0.f, 0.f, 0.f, 0.f};
    ((float4*)poolctx)[tid] = z;  // 512 threads x float4 = 2048 floats
  }
  // ---- stage A: enc1, K=512, 16 k-steps, depth-4 prefetch
  {
    f32x4 acc0 = (f32x4){0.f, 0.f, 0.f, 0.f};
    f32x4 acc1 = (f32x4){0.f, 0.f, 0.f, 0.f};
    const float* ap = me + (size_t)(row0 + m) * 512 + q * 8;
    const float* bp0 = w1f + (size_t)(w * 32 + m) * 512 + q * 8;
    const float* bp1 = w1f + (size_t)(w * 32 + 16 + m) * 512 + q * 8;
    float4 pa[4][2], pb[4][2][2];
#pragma unroll
    for (int d = 0; d < 4; ++d) {
      pa[d][0] = *(const float4*)(ap + d * 32);
      pa[d][1] = *(const float4*)(ap + d * 32 + 4);
      pb[d][0][0] = *(const float4*)(bp0 + d * 32);
      pb[d][0][1] = *(const float4*)(bp0 + d * 32 + 4);
      pb[d][1][0] = *(const float4*)(bp1 + d * 32);
      pb[d][1][1] = *(const float4*)(bp1 + d * 32 + 4);
    }
#pragma unroll
    for (int it = 0; it < 16; ++it) {
      int slot = it & 3;
      float4 a0 = pa[slot][0], a1 = pa[slot][1];
      float4 b00 = pb[slot][0][0], b01 = pb[slot][0][1];
      float4 b10 = pb[slot][1][0], b11 = pb[slot][1][1];
      if (it + 4 < 16) {
        pa[slot][0] = *(const float4*)(ap + (it + 4) * 32);
        pa[slot][1] = *(const float4*)(ap + (it + 4) * 32 + 4);
        pb[slot][0][0] = *(const float4*)(bp0 + (it + 4) * 32);
        pb[slot][0][1] = *(const float4*)(bp0 + (it + 4) * 32 + 4);
        pb[slot][1][0] = *(const float4*)(bp1 + (it + 4) * 32);
        pb[slot][1][1] = *(const float4*)(bp1 + (it + 4) * 32 + 4);
      }
      bf16x8 af = cvt8(a0, a1);
      acc0 = __builtin_amdgcn_mfma_f32_16x16x32_bf16(af, cvt8(b00, b01), acc0, 0, 0, 0);
      acc1 = __builtin_amdgcn_mfma_f32_16x16x32_bf16(af, cvt8(b10, b11), acc1, 0, 0, 0);
    }
#pragma unroll
    for (int nt = 0; nt < 2; ++nt) {
      int col = w * 32 + nt * 16 + m;
      float bias = b1[col];
      f32x4 a = nt ? acc1 : acc0;
#pragma unroll
      for (int reg = 0; reg < 4; ++reg)
        hh[(q * 4 + reg) * 260 + col] = a[reg] + bias;
    }
  }
  __syncthreads();
  // ---- LN + relu -> rA (bf16): 8 waves x 2 rows
  {
    float4 g4 = *(const float4*)(g + lane * 4);
    float4 lb4 = *(const float4*)(lb + lane * 4);
#pragma unroll
    for (int rr = 0; rr < 2; ++rr) {
      int r = w * 2 + rr;
      float4 v = *(const float4*)&hh[r * 260 + lane * 4];
      float s1 = v.x + v.y + v.z + v.w;
      float s2 = v.x * v.x + v.y * v.y + v.z * v.z + v.w * v.w;
#pragma unroll
      for (int o = 32; o > 0; o >>= 1) {
        s1 += __shfl_xor(s1, o, 64);
        s2 += __shfl_xor(s2, o, 64);
      }
      float mu = s1 * (1.f / 256.f);
      float var = s2 * (1.f / 256.f) - mu * mu;
      float rs = rsqrtf(var + 1e-5f);
      unsigned short y0 = (unsigned short)f2b(fmaxf((v.x - mu) * rs * g4.x + lb4.x, 0.f));
      unsigned short y1 = (unsigned short)f2b(fmaxf((v.y - mu) * rs * g4.y + lb4.y, 0.f));
      unsigned short y2 = (unsigned short)f2b(fmaxf((v.z - mu) * rs * g4.z + lb4.z, 0.f));
      unsigned short y3 = (unsigned short)f2b(fmaxf((v.w - mu) * rs * g4.w + lb4.w, 0.f));
      uint2 pk;
      pk.x = (unsigned)y0 | ((unsigned)y1 << 16);
      pk.y = (unsigned)y2 | ((unsigned)y3 << 16);
      *(uint2*)&rA[r * 264 + lane * 4] = pk;
    }
  }
  __syncthreads();
  // ---- stage B: enc2 (K=256), 8 k-steps, depth-4 prefetch on fp32 W
  {
    f32x4 acc0 = (f32x4){0.f, 0.f, 0.f, 0.f};
    f32x4 acc1 = (f32x4){0.f, 0.f, 0.f, 0.f};
    const float* cp0 = w2f + (size_t)(w * 32 + m) * 256 + q * 8;
    const float* cp1 = w2f + (size_t)(w * 32 + 16 + m) * 256 + q * 8;
    float4 pb[4][2][2];
#pragma unroll
    for (int d = 0; d < 4; ++d) {
      pb[d][0][0] = *(const float4*)(cp0 + d * 32);
      pb[d][0][1] = *(const float4*)(cp0 + d * 32 + 4);
      pb[d][1][0] = *(const float4*)(cp1 + d * 32);
      pb[d][1][1] = *(const float4*)(cp1 + d * 32 + 4);
    }
#pragma unroll
    for (int it = 0; it < 8; ++it) {
      int slot = it & 3;
      float4 b00 = pb[slot][0][0], b01 = pb[slot][0][1];
      float4 b10 = pb[slot][1][0], b11 = pb[slot][1][1];
      if (it + 4 < 8) {
        pb[slot][0][0] = *(const float4*)(cp0 + (it + 4) * 32);
        pb[slot][0][1] = *(const float4*)(cp0 + (it + 4) * 32 + 4);
        pb[slot][1][0] = *(const float4*)(cp1 + (it + 4) * 32);
        pb[slot][1][1] = *(const float4*)(cp1 + (it + 4) * 32 + 4);
      }
      bf16x8 af = *(const bf16x8*)&rA[m * 264 + it * 32 + q * 8];
      acc0 = __builtin_amdgcn_mfma_f32_16x16x32_bf16(af, cvt8(b00, b01), acc0, 0, 0, 0);
      acc1 = __builtin_amdgcn_mfma_f32_16x16x32_bf16(af, cvt8(b10, b11), acc1, 0, 0, 0);
    }
#pragma unroll
    for (int nt = 0; nt < 2; ++nt) {
      int col = w * 32 + nt * 16 + m;
      float bias = b2[col];
      f32x4 a = nt ? acc1 : acc0;
#pragma unroll
      for (int reg = 0; reg < 4; ++reg)
        mfs[(q * 4 + reg) * 256 + col] = (unsigned short)f2b(a[reg] + bias);
    }
  }
  __syncthreads();
  // coalesced copy-out: 16 rows x 256 ushort = 512 uint4, 512 threads
  {
    const uint4* src = (const uint4*)mfs;
    uint4* dst = (uint4*)(mfb + (size_t)row0 * 256);
    dst[tid] = src[tid];
  }
}

// ---------------------------------------------------------------------------
// K2: five 2048x256x256 GEMMs (q,k,v,a,b) — grid (128, 5), fp32 weights
// converted in-register (in_proj_w stride 256; con_w1 stride 512).
// ---------------------------------------------------------------------------
__global__ __launch_bounds__(256) void k_proj5(
    const unsigned short* __restrict__ mfb,
    const float* __restrict__ wq, const float* __restrict__ wc,
    const float* __restrict__ bq, const float* __restrict__ cb1,
    float* __restrict__ qkv, float* __restrict__ amat,
    float* __restrict__ bmat) {
  int tid = threadIdx.x, lane = tid & 63, w = tid >> 6;
  int row0 = blockIdx.x * 16;
  int part = blockIdx.y;
  int m = lane & 15, q = lane >> 4;
  const float* Wbase;
  size_t wstride;
  if (part < 3) { Wbase = wq + (size_t)part * 256 * 256; wstride = 256; }
  else { Wbase = wc + (part == 4 ? 256 : 0); wstride = 512; }
  // preload all 8 A-frags (bf16 from mfb)
  bf16x8 a[8];
#pragma unroll
  for (int ks = 0; ks < 8; ++ks)
    a[ks] = *(const bf16x8*)(mfb + (size_t)(row0 + m) * 256 + ks * 32 + q * 8);
  f32x4 acc[4];
#pragma unroll
  for (int i = 0; i < 4; ++i) acc[i] = (f32x4){0.f, 0.f, 0.f, 0.f};
  const float* bp[4];
#pragma unroll
  for (int nt = 0; nt < 4; ++nt)
    bp[nt] = Wbase + (size_t)(w * 64 + nt * 16 + m) * wstride + q * 8;
  float4 pb[4][4][2];
#pragma unroll
  for (int d = 0; d < 4; ++d)
#pragma unroll
    for (int nt = 0; nt < 4; ++nt) {
      pb[d][nt][0] = *(const float4*)(bp[nt] + d * 32);
      pb[d][nt][1] = *(const float4*)(bp[nt] + d * 32 + 4);
    }
#pragma unroll
  for (int it = 0; it < 8; ++it) {
    int slot = it & 3;
    float4 b0l = pb[slot][0][0], b0h = pb[slot][0][1];
    float4 b1l = pb[slot][1][0], b1h = pb[slot][1][1];
    float4 b2l = pb[slot][2][0], b2h = pb[slot][2][1];
    float4 b3l = pb[slot][3][0], b3h = pb[slot][3][1];
    if (it + 4 < 8) {
#pragma unroll
      for (int nt = 0; nt < 4; ++nt) {
        pb[slot][nt][0] = *(const float4*)(bp[nt] + (it + 4) * 32);
        pb[slot][nt][1] = *(const float4*)(bp[nt] + (it + 4) * 32 + 4);
      }
    }
    acc[0] = __builtin_amdgcn_mfma_f32_16x16x32_bf16(a[it], cvt8(b0l, b0h), acc[0], 0, 0, 0);
    acc[1] = __builtin_amdgcn_mfma_f32_16x16x32_bf16(a[it], cvt8(b1l, b1h), acc[1], 0, 0, 0);
    acc[2] = __builtin_amdgcn_mfma_f32_16x16x32_bf16(a[it], cvt8(b2l, b2h), acc[2], 0, 0, 0);
    acc[3] = __builtin_amdgcn_mfma_f32_16x16x32_bf16(a[it], cvt8(b3l, b3h), acc[3], 0, 0, 0);
  }
#pragma unroll
  for (int nt = 0; nt < 4; ++nt) {
    int col = w * 64 + nt * 16 + m;
    float bias;
    float* dst;
    int ld;
    if (part < 3) { bias = bq[part * 256 + col]; dst = qkv + part * 256; ld = 768; }
    else if (part == 3) { bias = cb1[col]; dst = amat; ld = 256; }
    else { bias = 0.f; dst = bmat; ld = 256; }
#pragma unroll
    for (int reg = 0; reg < 4; ++reg) {
      int row = row0 + q * 4 + reg;
      dst[(size_t)row * ld + col] = acc[nt][reg] + bias;
    }
  }
}

// ---------------------------------------------------------------------------
// ATTN fused: QK^T (fp32 VALU) + softmax + PV (bf16 MFMA) + pooled-ctx
// atomics. attn written bf16. grid = (b,h,sg) = 512 blocks.
// ---------------------------------------------------------------------------
__global__ __launch_bounds__(256) void k_attn_fused(
    const float* __restrict__ qkv, unsigned short* __restrict__ attnb,
    float* __restrict__ poolctx) {
  __shared__ float qs[32 * 32];
  __shared__ unsigned short ps[32 * 264];
  __shared__ unsigned short vt[32 * 264];
  int blk = blockIdx.x;
  int sg = blk & 7, bh = blk >> 3, h = bh & 7, b = bh >> 3;
  int tid = threadIdx.x, lane = tid & 63, w = tid >> 6;
  {
    int r = tid >> 3, c4 = tid & 7;
    float4 v = *(const float4*)(qkv + ((size_t)(b * 256 + sg * 32 + r)) * 768 + h * 32 + c4 * 4);
    *(float4*)&qs[r * 32 + c4 * 4] = v;
  }
  {
    const float4* vr = (const float4*)(qkv + ((size_t)(b * 256 + tid)) * 768 + 512 + h * 32);
#pragma unroll
    for (int d4 = 0; d4 < 8; ++d4) {
      float4 vv = vr[d4];
      vt[(d4 * 4 + 0) * 264 + tid] = (unsigned short)f2b(vv.x);
      vt[(d4 * 4 + 1) * 264 + tid] = (unsigned short)f2b(vv.y);
      vt[(d4 * 4 + 2) * 264 + tid] = (unsigned short)f2b(vv.z);
      vt[(d4 * 4 + 3) * 264 + tid] = (unsigned short)f2b(vv.w);
    }
  }
  __syncthreads();
  int r0 = w * 8;
  float sc[8][4];
#pragma unroll
  for (int r = 0; r < 8; ++r)
#pragma unroll
    for (int tt = 0; tt < 4; ++tt) sc[r][tt] = 0.f;
#pragma unroll
  for (int tt = 0; tt < 4; ++tt) {
    int t = tt * 64 + lane;
    const float4* kp = (const float4*)(qkv + ((size_t)(b * 256 + t)) * 768 + 256 + h * 32);
#pragma unroll
    for (int d4 = 0; d4 < 8; ++d4) {
      float4 kv = kp[d4];
#pragma unroll
      for (int r = 0; r < 8; ++r) {
        float4 qv = *(const float4*)&qs[(r0 + r) * 32 + d4 * 4];
        sc[r][tt] += qv.x * kv.x + qv.y * kv.y + qv.z * kv.z + qv.w * kv.w;
      }
    }
  }
  const float scale = 0.17677669529663689f;
  for (int r = 0; r < 8; ++r) {
    float v0 = sc[r][0] * scale, v1 = sc[r][1] * scale;
    float v2 = sc[r][2] * scale, v3 = sc[r][3] * scale;
    float mx = fmaxf(fmaxf(v0, v1), fmaxf(v2, v3));
#pragma unroll
    for (int o = 32; o > 0; o >>= 1) mx = fmaxf(mx, __shfl_xor(mx, o, 64));
    float e0 = expf(v0 - mx), e1 = expf(v1 - mx), e2 = expf(v2 - mx), e3 = expf(v3 - mx);
    float s = e0 + e1 + e2 + e3;
#pragma unroll
    for (int o = 32; o > 0; o >>= 1) s += __shfl_xor(s, o, 64);
    float inv = 1.f / s;
    unsigned short* prow = ps + (r0 + r) * 264;
    prow[lane] = (unsigned short)f2b(e0 * inv);
    prow[64 + lane] = (unsigned short)f2b(e1 * inv);
    prow[128 + lane] = (unsigned short)f2b(e2 * inv);
    prow[192 + lane] = (unsigned short)f2b(e3 * inv);
  }
  __syncthreads();
  {
    int r = tid >> 3, seg = tid & 7;
    const uint4* src = (const uint4*)&ps[r * 264 + seg * 32];
    uint4* dst = (uint4*)(attnb + ((size_t)(bh * 256 + sg * 32 + r)) * 256 + seg * 32);
    dst[0] = src[0]; dst[1] = src[1]; dst[2] = src[2]; dst[3] = src[3];
  }
  {
    int mt = w & 1, dt = w >> 1;
    int mm = lane & 15, qq = lane >> 4;
    f32x4 a = (f32x4){0.f, 0.f, 0.f, 0.f};
#pragma unroll
    for (int ks = 0; ks < 256; ks += 32) {
      bf16x8 af = *(const bf16x8*)&ps[(mt * 16 + mm) * 264 + ks + qq * 8];
      bf16x8 bf = *(const bf16x8*)&vt[(dt * 16 + mm) * 264 + ks + qq * 8];
      a = __builtin_amdgcn_mfma_f32_16x16x32_bf16(af, bf, a, 0, 0, 0);
    }
    float colsum = a[0] + a[1] + a[2] + a[3];
    colsum += __shfl_xor(colsum, 16, 64);
    colsum += __shfl_xor(colsum, 32, 64);
    if (lane < 16)
      atomicAdd(&poolctx[b * 256 + h * 32 + dt * 16 + mm], colsum);
  }
}

// ---------------------------------------------------------------------------
// TAIL: blocks [0,288) pair scores; [288,544) attn mean; [544,552) heads.
// ---------------------------------------------------------------------------
__global__ __launch_bounds__(256) void k_tail(
    const float* __restrict__ amat, const float* __restrict__ bmat,
    const float* __restrict__ conw2, const float* __restrict__ conb2,
    float* __restrict__ M,
    const unsigned short* __restrict__ attnb, float* __restrict__ out_aw,
    const float* __restrict__ poolctx,
    const float* __restrict__ outw, const float* __restrict__ outb,
    const float* __restrict__ cw1, const float* __restrict__ cb1h,
    const float* __restrict__ cw2, const float* __restrict__ cb2,
    const float* __restrict__ hw1, const float* __restrict__ hb1,
    const float* __restrict__ hw2, const float* __restrict__ hb2,
    float* __restrict__ out) {
  __shared__ float smem[32 * 132 * 2 + 256];
  int bx = blockIdx.x, tid = threadIdx.x;
  if (bx < 288) {
    // ---- pair scores, 32x32 upper-tri tiles, float4 LDS (stride 132)
    float* As = smem;
    float* Bs = smem + 32 * 132;
    float* w2s = smem + 32 * 132 * 2;
    int b = bx / 36, tix = bx % 36;
    int it = 0, rem = tix;
    while (rem >= 8 - it) { rem -= 8 - it; ++it; }
    int jt = it + rem;
    int tj = tid & 15, ti = tid >> 4;
    w2s[tid] = conw2[tid];
    float acc00 = 0, acc01 = 0, acc10 = 0, acc11 = 0;
    const float* Ab = amat + ((size_t)(b * 256 + it * 32)) * 256;
    const float* Bb = bmat + ((size_t)(b * 256 + jt * 32)) * 256;
    for (int ch = 0; ch < 2; ++ch) {
      __syncthreads();
#pragma unroll
      for (int k = 0; k < 4; ++k) {
        int f = tid + k * 256;
        int r = f >> 5, c4 = f & 31;
        float4 va = *(const float4*)(Ab + (size_t)r * 256 + ch * 128 + c4 * 4);
        float4 vb = *(const float4*)(Bb + (size_t)r * 256 + ch * 128 + c4 * 4);
        *(float4*)&As[r * 132 + c4 * 4] = va;
        *(float4*)&Bs[r * 132 + c4 * 4] = vb;
      }
      __syncthreads();
      const float* a0 = As + (2 * ti) * 132;
      const float* a1 = a0 + 132;
      const float* b0 = Bs + (2 * tj) * 132;
      const float* b1 = b0 + 132;
      const float* w2c = w2s + ch * 128;
      for (int d = 0; d < 128; d += 4) {
        float4 wv = *(const float4*)&w2c[d];
        float4 av0 = *(const float4*)&a0[d];
        float4 av1 = *(const float4*)&a1[d];
        float4 bv0 = *(const float4*)&b0[d];
        float4 bv1 = *(const float4*)&b1[d];
        acc00 += fmaxf(av0.x + bv0.x, 0.f) * wv.x + fmaxf(av0.y + bv0.y, 0.f) * wv.y
               + fmaxf(av0.z + bv0.z, 0.f) * wv.z + fmaxf(av0.w + bv0.w, 0.f) * wv.w;
        acc01 += fmaxf(av0.x + bv1.x, 0.f) * wv.x + fmaxf(av0.y + bv1.y, 0.f) * wv.y
               + fmaxf(av0.z + bv1.z, 0.f) * wv.z + fmaxf(av0.w + bv1.w, 0.f) * wv.w;
        acc10 += fmaxf(av1.x + bv0.x, 0.f) * wv.x + fmaxf(av1.y + bv0.y, 0.f) * wv.y
               + fmaxf(av1.z + bv0.z, 0.f) * wv.z + fmaxf(av1.w + bv0.w, 0.f) * wv.w;
        acc11 += fmaxf(av1.x + bv1.x, 0.f) * wv.x + fmaxf(av1.y + bv1.y, 0.f) * wv.y
               + fmaxf(av1.z + bv1.z, 0.f) * wv.z + fmaxf(av1.w + bv1.w, 0.f) * wv.w;
      }
    }
    float c2 = conb2[0];
    float s00 = 1.f / (1.f + expf(-(acc00 + c2)));
    float s01 = 1.f / (1.f + expf(-(acc01 + c2)));
    float s10 = 1.f / (1.f + expf(-(acc10 + c2)));
    float s11 = 1.f / (1.f + expf(-(acc11 + c2)));
    float* Mb = M + ((size_t)b << 16);
    int i0 = it * 32 + 2 * ti, i1 = i0 + 1;
    int j0 = jt * 32 + 2 * tj, j1 = j0 + 1;
    if (it != jt) {
      Mb[i0 * 256 + j0] = s00; Mb[j0 * 256 + i0] = s00;
      Mb[i0 * 256 + j1] = s01; Mb[j1 * 256 + i0] = s01;
      Mb[i1 * 256 + j0] = s10; Mb[j0 * 256 + i1] = s10;
      Mb[i1 * 256 + j1] = s11; Mb[j1 * 256 + i1] = s11;
    } else {
      if (j0 > i0) { Mb[i0 * 256 + j0] = s00; Mb[j0 * 256 + i0] = s00; }
      else if (j0 == i0) Mb[i0 * 256 + j0] = 0.f;
      if (j1 > i0) { Mb[i0 * 256 + j1] = s01; Mb[j1 * 256 + i0] = s01; }
      if (j0 > i1) { Mb[i1 * 256 + j0] = s10; Mb[j0 * 256 + i1] = s10; }
      if (j1 > i1) { Mb[i1 * 256 + j1] = s11; Mb[j1 * 256 + i1] = s11; }
      else if (j1 == i1) Mb[i1 * 256 + j1] = 0.f;
    }
  } else if (bx < 544) {
    // ---- attn mean over heads (bf16 in, fp32 out)
    int gid = (bx - 288) * 256 + tid;
    int b = gid >> 13, e8 = gid & 8191;
    size_t e = (size_t)e8 * 8;
    float s0 = 0, s1 = 0, s2 = 0, s3 = 0, s4 = 0, s5 = 0, s6 = 0, s7 = 0;
#pragma unroll
    for (int h = 0; h < 8; ++h) {
      uint4 v = *(const uint4*)(attnb + (((size_t)(b * 8 + h)) << 16) + e);
      s0 += __uint_as_float(v.x << 16); s1 += __uint_as_float(v.x & 0xffff0000u);
      s2 += __uint_as_float(v.y << 16); s3 += __uint_as_float(v.y & 0xffff0000u);
      s4 += __uint_as_float(v.z << 16); s5 += __uint_as_float(v.z & 0xffff0000u);
      s6 += __uint_as_float(v.w << 16); s7 += __uint_as_float(v.w & 0xffff0000u);
    }
    float* dst = out_aw + ((size_t)b << 16) + e;
    float4 r0 = {s0 * 0.125f, s1 * 0.125f, s2 * 0.125f, s3 * 0.125f};
    float4 r1 = {s4 * 0.125f, s5 * 0.125f, s6 * 0.125f, s7 * 0.125f};
    *(float4*)dst = r0;
    *(float4*)(dst + 4) = r1;
  } else {
    // ---- heads: pooled -> out-proj -> cons/hall
    float* pc = smem;
    float* psh = smem + 256;
    float* red = smem + 512;
    int b = bx - 544, j = tid;
    pc[j] = poolctx[b * 256 + j] * (1.f / 256.f);
    __syncthreads();
    float s = outb[j];
    const float4* wr = (const float4*)(outw + (size_t)j * 256);
    for (int k4 = 0; k4 < 64; ++k4) {
      float4 wv = wr[k4];
      const float* p = pc + k4 * 4;
      s += p[0] * wv.x + p[1] * wv.y + p[2] * wv.z + p[3] * wv.w;
    }
    psh[j] = s;
    __syncthreads();
    int jj = j & 127;
    bool isH = j >= 128;
    const float* w1 = isH ? hw1 : cw1;
    const float* bb1 = isH ? hb1 : cb1h;
    const float* w2 = isH ? hw2 : cw2;
    float a = bb1[jj];
    const float4* w1r = (const float4*)(w1 + (size_t)jj * 256);
    for (int k4 = 0; k4 < 64; ++k4) {
      float4 wv = w1r[k4];
      const float* p = psh + k4 * 4;
      a += p[0] * wv.x + p[1] * wv.y + p[2] * wv.z + p[3] * wv.w;
    }
    float v = fmaxf(a, 0.f) * w2[jj];
#pragma unroll
    for (int o = 32; o > 0; o >>= 1) v += __shfl_xor(v, o, 64);
    if ((j & 63) == 0) red[j >> 6] = v;
    __syncthreads();
    if (j == 0) {
      float c = red[0] + red[1] + cb2[0];
      float h = red[2] + red[3] + hb2[0];
      out[b] = 1.f / (1.f + expf(-c));
      out[8 + b] = 1.f / (1.f + expf(-h));
    }
  }
}

// ---------------------------------------------------------------------------
extern "C" void kernel_launch(void* const* d_in, const int* in_sizes, int n_in,
                              void* d_out, int out_size, void* d_ws, size_t ws_size,
                              hipStream_t stream) {
  const float* me        = (const float*)d_in[0];
  const float* enc_w1    = (const float*)d_in[1];
  const float* enc_b1    = (const float*)d_in[2];
  const float* ln_g      = (const float*)d_in[3];
  const float* ln_b      = (const float*)d_in[4];
  const float* enc_w2    = (const float*)d_in[5];
  const float* enc_b2    = (const float*)d_in[6];
  const float* in_proj_w = (const float*)d_in[7];
  const float* in_proj_b = (const float*)d_in[8];
  const float* out_w     = (const float*)d_in[9];
  const float* out_b     = (const float*)d_in[10];
  const float* cons_w1   = (const float*)d_in[11];
  const float* cons_b1   = (const float*)d_in[12];
  const float* cons_w2   = (const float*)d_in[13];
  const float* cons_b2   = (const float*)d_in[14];
  const float* hall_w1   = (const float*)d_in[15];
  const float* hall_b1   = (const float*)d_in[16];
  const float* hall_w2   = (const float*)d_in[17];
  const float* hall_b2   = (const float*)d_in[18];
  const float* con_w1    = (const float*)d_in[19];
  const float* con_b1    = (const float*)d_in[20];
  const float* con_w2    = (const float*)d_in[21];
  const float* con_b2    = (const float*)d_in[22];

  // workspace layout (float offsets); attnb = 4,194,304 ushorts = 2,097,152 f
  float* ws = (float*)d_ws;
  float* qkv  = ws;                                        // [0, 1572864)
  unsigned short* attnb = (unsigned short*)(ws + 1572864); // [1572864, 3670016)
  float* amat = ws + 3670016;                              // [3670016, 4194304)
  float* bmat = ws + 4194304;                              // [4194304, 4718592)
  unsigned short* mfb = (unsigned short*)(ws + 4718592);   // [4718592, 4980736)
  float* poolctx = ws + 4980736;                           // [4980736, 4982784)

  float* out    = (float*)d_out;
  float* out_M  = out + 16;
  float* out_aw = out + 16 + 524288;

  k_enc<<<128, 512, 0, stream>>>(me, enc_w1, enc_b1, ln_g, ln_b,
                                 enc_w2, enc_b2, mfb, poolctx);
  k_proj5<<<dim3(128, 5), 256, 0, stream>>>(mfb, in_proj_w, con_w1,
                                            in_proj_b, con_b1,
                                            qkv, amat, bmat);
  k_attn_fused<<<512, 256, 0, stream>>>(qkv, attnb, poolctx);
  k_tail<<<552, 256, 0, stream>>>(amat, bmat, con_w2, con_b2, out_M,
                                  attnb, out_aw, poolctx,
                                  out_w, out_b,
                                  cons_w1, cons_b1, cons_w2, cons_b2,
                                  hall_w1, hall_b1, hall_w2, hall_b2, out);
}

// Round 9
// 194.050 us; speedup vs baseline: 1.0885x; 1.0885x over previous
//
#include <hip/hip_runtime.h>
#include <math.h>

typedef __attribute__((ext_vector_type(8))) short bf16x8;
typedef __attribute__((ext_vector_type(4))) float f32x4;

__device__ __forceinline__ short f2b(float f) {
  union { float f; unsigned u; } v; v.f = f;
  unsigned u = v.u + 0x7fffu + ((v.u >> 16) & 1u);
  return (short)(u >> 16);
}

// pack two float4 (8 consecutive fp32) into one bf16x8 fragment
__device__ __forceinline__ bf16x8 cvt8(float4 a, float4 b) {
  bf16x8 r;
  r[0] = f2b(a.x); r[1] = f2b(a.y); r[2] = f2b(a.z); r[3] = f2b(a.w);
  r[4] = f2b(b.x); r[5] = f2b(b.y); r[6] = f2b(b.z); r[7] = f2b(b.w);
  return r;
}

// ---------------------------------------------------------------------------
// K1: enc1 (K=512) + LN + relu -> enc2 (K=256) -> mf bf16. (unchanged)
// ---------------------------------------------------------------------------
__global__ __launch_bounds__(512) void k_enc(
    const float* __restrict__ me,
    const float* __restrict__ w1f, const float* __restrict__ b1,
    const float* __restrict__ g, const float* __restrict__ lb,
    const float* __restrict__ w2f, const float* __restrict__ b2,
    unsigned short* __restrict__ mfb, float* __restrict__ poolctx) {
  __shared__ float hh[16 * 260];
  __shared__ unsigned short rA[16 * 264];
  __shared__ unsigned short mfs[16 * 256];
  int tid = threadIdx.x, lane = tid & 63, w = tid >> 6;
  int row0 = blockIdx.x * 16;
  int m = lane & 15, q = lane >> 4;
  if (blockIdx.x == 0) {
    float4 z = {0.f, 0.f, 0.f, 0.f};
    ((float4*)poolctx)[tid] = z;
  }
  {
    f32x4 acc0 = (f32x4){0.f, 0.f, 0.f, 0.f};
    f32x4 acc1 = (f32x4){0.f, 0.f, 0.f, 0.f};
    const float* ap = me + (size_t)(row0 + m) * 512 + q * 8;
    const float* bp0 = w1f + (size_t)(w * 32 + m) * 512 + q * 8;
    const float* bp1 = w1f + (size_t)(w * 32 + 16 + m) * 512 + q * 8;
    float4 pa[4][2], pb[4][2][2];
#pragma unroll
    for (int d = 0; d < 4; ++d) {
      pa[d][0] = *(const float4*)(ap + d * 32);
      pa[d][1] = *(const float4*)(ap + d * 32 + 4);
      pb[d][0][0] = *(const float4*)(bp0 + d * 32);
      pb[d][0][1] = *(const float4*)(bp0 + d * 32 + 4);
      pb[d][1][0] = *(const float4*)(bp1 + d * 32);
      pb[d][1][1] = *(const float4*)(bp1 + d * 32 + 4);
    }
#pragma unroll
    for (int it = 0; it < 16; ++it) {
      int slot = it & 3;
      float4 a0 = pa[slot][0], a1 = pa[slot][1];
      float4 b00 = pb[slot][0][0], b01 = pb[slot][0][1];
      float4 b10 = pb[slot][1][0], b11 = pb[slot][1][1];
      if (it + 4 < 16) {
        pa[slot][0] = *(const float4*)(ap + (it + 4) * 32);
        pa[slot][1] = *(const float4*)(ap + (it + 4) * 32 + 4);
        pb[slot][0][0] = *(const float4*)(bp0 + (it + 4) * 32);
        pb[slot][0][1] = *(const float4*)(bp0 + (it + 4) * 32 + 4);
        pb[slot][1][0] = *(const float4*)(bp1 + (it + 4) * 32);
        pb[slot][1][1] = *(const float4*)(bp1 + (it + 4) * 32 + 4);
      }
      bf16x8 af = cvt8(a0, a1);
      acc0 = __builtin_amdgcn_mfma_f32_16x16x32_bf16(af, cvt8(b00, b01), acc0, 0, 0, 0);
      acc1 = __builtin_amdgcn_mfma_f32_16x16x32_bf16(af, cvt8(b10, b11), acc1, 0, 0, 0);
    }
#pragma unroll
    for (int nt = 0; nt < 2; ++nt) {
      int col = w * 32 + nt * 16 + m;
      float bias = b1[col];
      f32x4 a = nt ? acc1 : acc0;
#pragma unroll
      for (int reg = 0; reg < 4; ++reg)
        hh[(q * 4 + reg) * 260 + col] = a[reg] + bias;
    }
  }
  __syncthreads();
  {
    float4 g4 = *(const float4*)(g + lane * 4);
    float4 lb4 = *(const float4*)(lb + lane * 4);
#pragma unroll
    for (int rr = 0; rr < 2; ++rr) {
      int r = w * 2 + rr;
      float4 v = *(const float4*)&hh[r * 260 + lane * 4];
      float s1 = v.x + v.y + v.z + v.w;
      float s2 = v.x * v.x + v.y * v.y + v.z * v.z + v.w * v.w;
#pragma unroll
      for (int o = 32; o > 0; o >>= 1) {
        s1 += __shfl_xor(s1, o, 64);
        s2 += __shfl_xor(s2, o, 64);
      }
      float mu = s1 * (1.f / 256.f);
      float var = s2 * (1.f / 256.f) - mu * mu;
      float rs = rsqrtf(var + 1e-5f);
      unsigned short y0 = (unsigned short)f2b(fmaxf((v.x - mu) * rs * g4.x + lb4.x, 0.f));
      unsigned short y1 = (unsigned short)f2b(fmaxf((v.y - mu) * rs * g4.y + lb4.y, 0.f));
      unsigned short y2 = (unsigned short)f2b(fmaxf((v.z - mu) * rs * g4.z + lb4.z, 0.f));
      unsigned short y3 = (unsigned short)f2b(fmaxf((v.w - mu) * rs * g4.w + lb4.w, 0.f));
      uint2 pk;
      pk.x = (unsigned)y0 | ((unsigned)y1 << 16);
      pk.y = (unsigned)y2 | ((unsigned)y3 << 16);
      *(uint2*)&rA[r * 264 + lane * 4] = pk;
    }
  }
  __syncthreads();
  {
    f32x4 acc0 = (f32x4){0.f, 0.f, 0.f, 0.f};
    f32x4 acc1 = (f32x4){0.f, 0.f, 0.f, 0.f};
    const float* cp0 = w2f + (size_t)(w * 32 + m) * 256 + q * 8;
    const float* cp1 = w2f + (size_t)(w * 32 + 16 + m) * 256 + q * 8;
    float4 pb[4][2][2];
#pragma unroll
    for (int d = 0; d < 4; ++d) {
      pb[d][0][0] = *(const float4*)(cp0 + d * 32);
      pb[d][0][1] = *(const float4*)(cp0 + d * 32 + 4);
      pb[d][1][0] = *(const float4*)(cp1 + d * 32);
      pb[d][1][1] = *(const float4*)(cp1 + d * 32 + 4);
    }
#pragma unroll
    for (int it = 0; it < 8; ++it) {
      int slot = it & 3;
      float4 b00 = pb[slot][0][0], b01 = pb[slot][0][1];
      float4 b10 = pb[slot][1][0], b11 = pb[slot][1][1];
      if (it + 4 < 8) {
        pb[slot][0][0] = *(const float4*)(cp0 + (it + 4) * 32);
        pb[slot][0][1] = *(const float4*)(cp0 + (it + 4) * 32 + 4);
        pb[slot][1][0] = *(const float4*)(cp1 + (it + 4) * 32);
        pb[slot][1][1] = *(const float4*)(cp1 + (it + 4) * 32 + 4);
      }
      bf16x8 af = *(const bf16x8*)&rA[m * 264 + it * 32 + q * 8];
      acc0 = __builtin_amdgcn_mfma_f32_16x16x32_bf16(af, cvt8(b00, b01), acc0, 0, 0, 0);
      acc1 = __builtin_amdgcn_mfma_f32_16x16x32_bf16(af, cvt8(b10, b11), acc1, 0, 0, 0);
    }
#pragma unroll
    for (int nt = 0; nt < 2; ++nt) {
      int col = w * 32 + nt * 16 + m;
      float bias = b2[col];
      f32x4 a = nt ? acc1 : acc0;
#pragma unroll
      for (int reg = 0; reg < 4; ++reg)
        mfs[(q * 4 + reg) * 256 + col] = (unsigned short)f2b(a[reg] + bias);
    }
  }
  __syncthreads();
  {
    const uint4* src = (const uint4*)mfs;
    uint4* dst = (uint4*)(mfb + (size_t)row0 * 256);
    dst[tid] = src[tid];
  }
}

// ---------------------------------------------------------------------------
// K2: five 2048x256x256 GEMMs (q,k,v,a,b) — unchanged
// ---------------------------------------------------------------------------
__global__ __launch_bounds__(256) void k_proj5(
    const unsigned short* __restrict__ mfb,
    const float* __restrict__ wq, const float* __restrict__ wc,
    const float* __restrict__ bq, const float* __restrict__ cb1,
    float* __restrict__ qkv, float* __restrict__ amat,
    float* __restrict__ bmat) {
  int tid = threadIdx.x, lane = tid & 63, w = tid >> 6;
  int row0 = blockIdx.x * 16;
  int part = blockIdx.y;
  int m = lane & 15, q = lane >> 4;
  const float* Wbase;
  size_t wstride;
  if (part < 3) { Wbase = wq + (size_t)part * 256 * 256; wstride = 256; }
  else { Wbase = wc + (part == 4 ? 256 : 0); wstride = 512; }
  bf16x8 a[8];
#pragma unroll
  for (int ks = 0; ks < 8; ++ks)
    a[ks] = *(const bf16x8*)(mfb + (size_t)(row0 + m) * 256 + ks * 32 + q * 8);
  f32x4 acc[4];
#pragma unroll
  for (int i = 0; i < 4; ++i) acc[i] = (f32x4){0.f, 0.f, 0.f, 0.f};
  const float* bp[4];
#pragma unroll
  for (int nt = 0; nt < 4; ++nt)
    bp[nt] = Wbase + (size_t)(w * 64 + nt * 16 + m) * wstride + q * 8;
  float4 pb[4][4][2];
#pragma unroll
  for (int d = 0; d < 4; ++d)
#pragma unroll
    for (int nt = 0; nt < 4; ++nt) {
      pb[d][nt][0] = *(const float4*)(bp[nt] + d * 32);
      pb[d][nt][1] = *(const float4*)(bp[nt] + d * 32 + 4);
    }
#pragma unroll
  for (int it = 0; it < 8; ++it) {
    int slot = it & 3;
    float4 b0l = pb[slot][0][0], b0h = pb[slot][0][1];
    float4 b1l = pb[slot][1][0], b1h = pb[slot][1][1];
    float4 b2l = pb[slot][2][0], b2h = pb[slot][2][1];
    float4 b3l = pb[slot][3][0], b3h = pb[slot][3][1];
    if (it + 4 < 8) {
#pragma unroll
      for (int nt = 0; nt < 4; ++nt) {
        pb[slot][nt][0] = *(const float4*)(bp[nt] + (it + 4) * 32);
        pb[slot][nt][1] = *(const float4*)(bp[nt] + (it + 4) * 32 + 4);
      }
    }
    acc[0] = __builtin_amdgcn_mfma_f32_16x16x32_bf16(a[it], cvt8(b0l, b0h), acc[0], 0, 0, 0);
    acc[1] = __builtin_amdgcn_mfma_f32_16x16x32_bf16(a[it], cvt8(b1l, b1h), acc[1], 0, 0, 0);
    acc[2] = __builtin_amdgcn_mfma_f32_16x16x32_bf16(a[it], cvt8(b2l, b2h), acc[2], 0, 0, 0);
    acc[3] = __builtin_amdgcn_mfma_f32_16x16x32_bf16(a[it], cvt8(b3l, b3h), acc[3], 0, 0, 0);
  }
#pragma unroll
  for (int nt = 0; nt < 4; ++nt) {
    int col = w * 64 + nt * 16 + m;
    float bias;
    float* dst;
    int ld;
    if (part < 3) { bias = bq[part * 256 + col]; dst = qkv + part * 256; ld = 768; }
    else if (part == 3) { bias = cb1[col]; dst = amat; ld = 256; }
    else { bias = 0.f; dst = bmat; ld = 256; }
#pragma unroll
    for (int reg = 0; reg < 4; ++reg) {
      int row = row0 + q * 4 + reg;
      dst[(size_t)row * ld + col] = acc[nt][reg] + bias;
    }
  }
}

// ---------------------------------------------------------------------------
// ATTN v3: all-MFMA. QK^T (bf16 MFMA from LDS) -> in-register softmax ->
// PV (bf16 MFMA) + attnb write + pooled atomics. grid = 512 blocks.
// Wave w: mt = w&1 (16-row half), ng = w>>1 (128-col half).
// ---------------------------------------------------------------------------
__global__ __launch_bounds__(256) void k_attn_mfma(
    const float* __restrict__ qkv, unsigned short* __restrict__ attnb,
    float* __restrict__ poolctx) {
  __shared__ unsigned short qs[32 * 40];   // Q bf16, stride 40 (16B-aligned rows)
  __shared__ unsigned short kb[256 * 40];  // K bf16
  __shared__ unsigned short vt[32 * 264];  // V^T bf16 [d][t]
  __shared__ unsigned short ps[32 * 264];  // P bf16 [s][t]
  __shared__ float redm[2][32];
  __shared__ float reds[2][32];
  int blk = blockIdx.x;
  int sg = blk & 7, bh = blk >> 3, h = bh & 7, b = bh >> 3;
  int tid = threadIdx.x, lane = tid & 63, w = tid >> 6;
  int m = lane & 15, q = lane >> 4;
  // stage Q (coalesced: 8 threads/row)
  {
    int r = tid >> 3, c4 = tid & 7;
    float4 v = *(const float4*)(qkv + ((size_t)(b * 256 + sg * 32 + r)) * 768 + h * 32 + c4 * 4);
    unsigned short* dst = &qs[r * 40 + c4 * 4];
    dst[0] = (unsigned short)f2b(v.x); dst[1] = (unsigned short)f2b(v.y);
    dst[2] = (unsigned short)f2b(v.z); dst[3] = (unsigned short)f2b(v.w);
  }
  // stage K (coalesced: 8 threads/row, 8 iterations)
#pragma unroll
  for (int i = 0; i < 8; ++i) {
    int f = i * 256 + tid;
    int r = f >> 3, c4 = f & 7;
    float4 v = *(const float4*)(qkv + ((size_t)(b * 256 + r)) * 768 + 256 + h * 32 + c4 * 4);
    unsigned short* dst = &kb[r * 40 + c4 * 4];
    dst[0] = (unsigned short)f2b(v.x); dst[1] = (unsigned short)f2b(v.y);
    dst[2] = (unsigned short)f2b(v.z); dst[3] = (unsigned short)f2b(v.w);
  }
  // stage V^T (lane = t)
  {
    const float4* vr = (const float4*)(qkv + ((size_t)(b * 256 + tid)) * 768 + 512 + h * 32);
#pragma unroll
    for (int d4 = 0; d4 < 8; ++d4) {
      float4 vv = vr[d4];
      vt[(d4 * 4 + 0) * 264 + tid] = (unsigned short)f2b(vv.x);
      vt[(d4 * 4 + 1) * 264 + tid] = (unsigned short)f2b(vv.y);
      vt[(d4 * 4 + 2) * 264 + tid] = (unsigned short)f2b(vv.z);
      vt[(d4 * 4 + 3) * 264 + tid] = (unsigned short)f2b(vv.w);
    }
  }
  __syncthreads();
  int mt = w & 1, ng = w >> 1;
  int lrow = mt * 16 + q * 4;  // first of this lane-quad's 4 local rows
  // QK^T: 8 n-tiles of 16 t's, K=32 in one MFMA each
  f32x4 acc[8];
  {
    bf16x8 af = *(const bf16x8*)&qs[(mt * 16 + m) * 40 + q * 8];
#pragma unroll
    for (int nt = 0; nt < 8; ++nt) {
      bf16x8 bf = *(const bf16x8*)&kb[(ng * 128 + nt * 16 + m) * 40 + q * 8];
      acc[nt] = __builtin_amdgcn_mfma_f32_16x16x32_bf16(
          af, bf, (f32x4){0.f, 0.f, 0.f, 0.f}, 0, 0, 0);
    }
  }
  const float scale = 0.17677669529663689f;
#pragma unroll
  for (int nt = 0; nt < 8; ++nt)
#pragma unroll
    for (int reg = 0; reg < 4; ++reg) acc[nt][reg] *= scale;
  // row max (partial over this wave's 128 cols)
  float pm[4];
#pragma unroll
  for (int reg = 0; reg < 4; ++reg) {
    float mx = acc[0][reg];
#pragma unroll
    for (int nt = 1; nt < 8; ++nt) mx = fmaxf(mx, acc[nt][reg]);
#pragma unroll
    for (int o = 1; o < 16; o <<= 1) mx = fmaxf(mx, __shfl_xor(mx, o, 64));
    pm[reg] = mx;
  }
  if (m == 0) {
#pragma unroll
    for (int reg = 0; reg < 4; ++reg) redm[ng][lrow + reg] = pm[reg];
  }
  __syncthreads();
  float inv[4];
  float psum[4];
#pragma unroll
  for (int reg = 0; reg < 4; ++reg) {
    float Mv = fmaxf(redm[0][lrow + reg], redm[1][lrow + reg]);
    float s = 0.f;
#pragma unroll
    for (int nt = 0; nt < 8; ++nt) {
      float e = __expf(acc[nt][reg] - Mv);
      acc[nt][reg] = e;
      s += e;
    }
#pragma unroll
    for (int o = 1; o < 16; o <<= 1) s += __shfl_xor(s, o, 64);
    psum[reg] = s;
  }
  if (m == 0) {
#pragma unroll
    for (int reg = 0; reg < 4; ++reg) reds[ng][lrow + reg] = psum[reg];
  }
  __syncthreads();
#pragma unroll
  for (int reg = 0; reg < 4; ++reg)
    inv[reg] = 1.f / (reds[0][lrow + reg] + reds[1][lrow + reg]);
  // write P (bf16) to ps
#pragma unroll
  for (int nt = 0; nt < 8; ++nt) {
    int t = ng * 128 + nt * 16 + m;
#pragma unroll
    for (int reg = 0; reg < 4; ++reg)
      ps[(lrow + reg) * 264 + t] = (unsigned short)f2b(acc[nt][reg] * inv[reg]);
  }
  __syncthreads();
  // copy P to attnb (coalesced; row base 264*2=528B is 16B-aligned)
  {
    int r = tid >> 3, seg = tid & 7;
    const uint4* src = (const uint4*)&ps[r * 264 + seg * 32];
    uint4* dst = (uint4*)(attnb + ((size_t)(bh * 256 + sg * 32 + r)) * 256 + seg * 32);
    dst[0] = src[0]; dst[1] = src[1]; dst[2] = src[2]; dst[3] = src[3];
  }
  // PV via MFMA: wave w -> (mt rows, dt d-half)
  {
    int dt = w >> 1;
    f32x4 a = (f32x4){0.f, 0.f, 0.f, 0.f};
#pragma unroll
    for (int ks = 0; ks < 256; ks += 32) {
      bf16x8 af = *(const bf16x8*)&ps[(mt * 16 + m) * 264 + ks + q * 8];
      bf16x8 bf = *(const bf16x8*)&vt[(dt * 16 + m) * 264 + ks + q * 8];
      a = __builtin_amdgcn_mfma_f32_16x16x32_bf16(af, bf, a, 0, 0, 0);
    }
    float colsum = a[0] + a[1] + a[2] + a[3];
    colsum += __shfl_xor(colsum, 16, 64);
    colsum += __shfl_xor(colsum, 32, 64);
    if (lane < 16)
      atomicAdd(&poolctx[b * 256 + h * 32 + dt * 16 + m], colsum);
  }
}

// ---------------------------------------------------------------------------
// TAIL: blocks [0,288) pair scores; [288,544) attn mean; [544,552) heads.
// ---------------------------------------------------------------------------
__global__ __launch_bounds__(256) void k_tail(
    const float* __restrict__ amat, const float* __restrict__ bmat,
    const float* __restrict__ conw2, const float* __restrict__ conb2,
    float* __restrict__ M,
    const unsigned short* __restrict__ attnb, float* __restrict__ out_aw,
    const float* __restrict__ poolctx,
    const float* __restrict__ outw, const float* __restrict__ outb,
    const float* __restrict__ cw1, const float* __restrict__ cb1h,
    const float* __restrict__ cw2, const float* __restrict__ cb2,
    const float* __restrict__ hw1, const float* __restrict__ hb1,
    const float* __restrict__ hw2, const float* __restrict__ hb2,
    float* __restrict__ out) {
  __shared__ float smem[32 * 132 * 2 + 256];
  int bx = blockIdx.x, tid = threadIdx.x;
  if (bx < 288) {
    float* As = smem;
    float* Bs = smem + 32 * 132;
    float* w2s = smem + 32 * 132 * 2;
    int b = bx / 36, tix = bx % 36;
    int it = 0, rem = tix;
    while (rem >= 8 - it) { rem -= 8 - it; ++it; }
    int jt = it + rem;
    int tj = tid & 15, ti = tid >> 4;
    w2s[tid] = conw2[tid];
    float acc00 = 0, acc01 = 0, acc10 = 0, acc11 = 0;
    const float* Ab = amat + ((size_t)(b * 256 + it * 32)) * 256;
    const float* Bb = bmat + ((size_t)(b * 256 + jt * 32)) * 256;
    for (int ch = 0; ch < 2; ++ch) {
      __syncthreads();
#pragma unroll
      for (int k = 0; k < 4; ++k) {
        int f = tid + k * 256;
        int r = f >> 5, c4 = f & 31;
        float4 va = *(const float4*)(Ab + (size_t)r * 256 + ch * 128 + c4 * 4);
        float4 vb = *(const float4*)(Bb + (size_t)r * 256 + ch * 128 + c4 * 4);
        *(float4*)&As[r * 132 + c4 * 4] = va;
        *(float4*)&Bs[r * 132 + c4 * 4] = vb;
      }
      __syncthreads();
      const float* a0 = As + (2 * ti) * 132;
      const float* a1 = a0 + 132;
      const float* b0 = Bs + (2 * tj) * 132;
      const float* b1 = b0 + 132;
      const float* w2c = w2s + ch * 128;
      for (int d = 0; d < 128; d += 4) {
        float4 wv = *(const float4*)&w2c[d];
        float4 av0 = *(const float4*)&a0[d];
        float4 av1 = *(const float4*)&a1[d];
        float4 bv0 = *(const float4*)&b0[d];
        float4 bv1 = *(const float4*)&b1[d];
        acc00 += fmaxf(av0.x + bv0.x, 0.f) * wv.x + fmaxf(av0.y + bv0.y, 0.f) * wv.y
               + fmaxf(av0.z + bv0.z, 0.f) * wv.z + fmaxf(av0.w + bv0.w, 0.f) * wv.w;
        acc01 += fmaxf(av0.x + bv1.x, 0.f) * wv.x + fmaxf(av0.y + bv1.y, 0.f) * wv.y
               + fmaxf(av0.z + bv1.z, 0.f) * wv.z + fmaxf(av0.w + bv1.w, 0.f) * wv.w;
        acc10 += fmaxf(av1.x + bv0.x, 0.f) * wv.x + fmaxf(av1.y + bv0.y, 0.f) * wv.y
               + fmaxf(av1.z + bv0.z, 0.f) * wv.z + fmaxf(av1.w + bv0.w, 0.f) * wv.w;
        acc11 += fmaxf(av1.x + bv1.x, 0.f) * wv.x + fmaxf(av1.y + bv1.y, 0.f) * wv.y
               + fmaxf(av1.z + bv1.z, 0.f) * wv.z + fmaxf(av1.w + bv1.w, 0.f) * wv.w;
      }
    }
    float c2 = conb2[0];
    float s00 = 1.f / (1.f + expf(-(acc00 + c2)));
    float s01 = 1.f / (1.f + expf(-(acc01 + c2)));
    float s10 = 1.f / (1.f + expf(-(acc10 + c2)));
    float s11 = 1.f / (1.f + expf(-(acc11 + c2)));
    float* Mb = M + ((size_t)b << 16);
    int i0 = it * 32 + 2 * ti, i1 = i0 + 1;
    int j0 = jt * 32 + 2 * tj, j1 = j0 + 1;
    if (it != jt) {
      Mb[i0 * 256 + j0] = s00; Mb[j0 * 256 + i0] = s00;
      Mb[i0 * 256 + j1] = s01; Mb[j1 * 256 + i0] = s01;
      Mb[i1 * 256 + j0] = s10; Mb[j0 * 256 + i1] = s10;
      Mb[i1 * 256 + j1] = s11; Mb[j1 * 256 + i1] = s11;
    } else {
      if (j0 > i0) { Mb[i0 * 256 + j0] = s00; Mb[j0 * 256 + i0] = s00; }
      else if (j0 == i0) Mb[i0 * 256 + j0] = 0.f;
      if (j1 > i0) { Mb[i0 * 256 + j1] = s01; Mb[j1 * 256 + i0] = s01; }
      if (j0 > i1) { Mb[i1 * 256 + j0] = s10; Mb[j0 * 256 + i1] = s10; }
      if (j1 > i1) { Mb[i1 * 256 + j1] = s11; Mb[j1 * 256 + i1] = s11; }
      else if (j1 == i1) Mb[i1 * 256 + j1] = 0.f;
    }
  } else if (bx < 544) {
    int gid = (bx - 288) * 256 + tid;
    int b = gid >> 13, e8 = gid & 8191;
    size_t e = (size_t)e8 * 8;
    float s0 = 0, s1 = 0, s2 = 0, s3 = 0, s4 = 0, s5 = 0, s6 = 0, s7 = 0;
#pragma unroll
    for (int h = 0; h < 8; ++h) {
      uint4 v = *(const uint4*)(attnb + (((size_t)(b * 8 + h)) << 16) + e);
      s0 += __uint_as_float(v.x << 16); s1 += __uint_as_float(v.x & 0xffff0000u);
      s2 += __uint_as_float(v.y << 16); s3 += __uint_as_float(v.y & 0xffff0000u);
      s4 += __uint_as_float(v.z << 16); s5 += __uint_as_float(v.z & 0xffff0000u);
      s6 += __uint_as_float(v.w << 16); s7 += __uint_as_float(v.w & 0xffff0000u);
    }
    float* dst = out_aw + ((size_t)b << 16) + e;
    float4 r0 = {s0 * 0.125f, s1 * 0.125f, s2 * 0.125f, s3 * 0.125f};
    float4 r1 = {s4 * 0.125f, s5 * 0.125f, s6 * 0.125f, s7 * 0.125f};
    *(float4*)dst = r0;
    *(float4*)(dst + 4) = r1;
  } else {
    float* pc = smem;
    float* psh = smem + 256;
    float* red = smem + 512;
    int b = bx - 544, j = tid;
    pc[j] = poolctx[b * 256 + j] * (1.f / 256.f);
    __syncthreads();
    float s = outb[j];
    const float4* wr = (const float4*)(outw + (size_t)j * 256);
    for (int k4 = 0; k4 < 64; ++k4) {
      float4 wv = wr[k4];
      const float* p = pc + k4 * 4;
      s += p[0] * wv.x + p[1] * wv.y + p[2] * wv.z + p[3] * wv.w;
    }
    psh[j] = s;
    __syncthreads();
    int jj = j & 127;
    bool isH = j >= 128;
    const float* w1 = isH ? hw1 : cw1;
    const float* bb1 = isH ? hb1 : cb1h;
    const float* w2 = isH ? hw2 : cw2;
    float a = bb1[jj];
    const float4* w1r = (const float4*)(w1 + (size_t)jj * 256);
    for (int k4 = 0; k4 < 64; ++k4) {
      float4 wv = w1r[k4];
      const float* p = psh + k4 * 4;
      a += p[0] * wv.x + p[1] * wv.y + p[2] * wv.z + p[3] * wv.w;
    }
    float v = fmaxf(a, 0.f) * w2[jj];
#pragma unroll
    for (int o = 32; o > 0; o >>= 1) v += __shfl_xor(v, o, 64);
    if ((j & 63) == 0) red[j >> 6] = v;
    __syncthreads();
    if (j == 0) {
      float c = red[0] + red[1] + cb2[0];
      float h = red[2] + red[3] + hb2[0];
      out[b] = 1.f / (1.f + expf(-c));
      out[8 + b] = 1.f / (1.f + expf(-h));
    }
  }
}

// ---------------------------------------------------------------------------
extern "C" void kernel_launch(void* const* d_in, const int* in_sizes, int n_in,
                              void* d_out, int out_size, void* d_ws, size_t ws_size,
                              hipStream_t stream) {
  const float* me        = (const float*)d_in[0];
  const float* enc_w1    = (const float*)d_in[1];
  const float* enc_b1    = (const float*)d_in[2];
  const float* ln_g      = (const float*)d_in[3];
  const float* ln_b      = (const float*)d_in[4];
  const float* enc_w2    = (const float*)d_in[5];
  const float* enc_b2    = (const float*)d_in[6];
  const float* in_proj_w = (const float*)d_in[7];
  const float* in_proj_b = (const float*)d_in[8];
  const float* out_w     = (const float*)d_in[9];
  const float* out_b     = (const float*)d_in[10];
  const float* cons_w1   = (const float*)d_in[11];
  const float* cons_b1   = (const float*)d_in[12];
  const float* cons_w2   = (const float*)d_in[13];
  const float* cons_b2   = (const float*)d_in[14];
  const float* hall_w1   = (const float*)d_in[15];
  const float* hall_b1   = (const float*)d_in[16];
  const float* hall_w2   = (const float*)d_in[17];
  const float* hall_b2   = (const float*)d_in[18];
  const float* con_w1    = (const float*)d_in[19];
  const float* con_b1    = (const float*)d_in[20];
  const float* con_w2    = (const float*)d_in[21];
  const float* con_b2    = (const float*)d_in[22];

  // workspace layout (float offsets); attnb = 4,194,304 ushorts = 2,097,152 f
  float* ws = (float*)d_ws;
  float* qkv  = ws;                                        // [0, 1572864)
  unsigned short* attnb = (unsigned short*)(ws + 1572864); // [1572864, 3670016)
  float* amat = ws + 3670016;                              // [3670016, 4194304)
  float* bmat = ws + 4194304;                              // [4194304, 4718592)
  unsigned short* mfb = (unsigned short*)(ws + 4718592);   // [4718592, 4980736)
  float* poolctx = ws + 4980736;                           // [4980736, 4982784)

  float* out    = (float*)d_out;
  float* out_M  = out + 16;
  float* out_aw = out + 16 + 524288;

  k_enc<<<128, 512, 0, stream>>>(me, enc_w1, enc_b1, ln_g, ln_b,
                                 enc_w2, enc_b2, mfb, poolctx);
  k_proj5<<<dim3(128, 5), 256, 0, stream>>>(mfb, in_proj_w, con_w1,
                                            in_proj_b, con_b1,
                                            qkv, amat, bmat);
  k_attn_mfma<<<512, 256, 0, stream>>>(qkv, attnb, poolctx);
  k_tail<<<552, 256, 0, stream>>>(amat, bmat, con_w2, con_b2, out_M,
                                  attnb, out_aw, poolctx,
                                  out_w, out_b,
                                  cons_w1, cons_b1, cons_w2, cons_b2,
                                  hall_w1, hall_b1, hall_w2, hall_b2, out);
}

// Round 10
// 180.899 us; speedup vs baseline: 1.1676x; 1.0727x over previous
//
#include <hip/hip_runtime.h>
#include <math.h>

typedef __attribute__((ext_vector_type(8))) short bf16x8;
typedef __attribute__((ext_vector_type(4))) float f32x4;

__device__ __forceinline__ short f2b(float f) {
  union { float f; unsigned u; } v; v.f = f;
  unsigned u = v.u + 0x7fffu + ((v.u >> 16) & 1u);
  return (short)(u >> 16);
}

__device__ __forceinline__ bf16x8 cvt8(float4 a, float4 b) {
  bf16x8 r;
  r[0] = f2b(a.x); r[1] = f2b(a.y); r[2] = f2b(a.z); r[3] = f2b(a.w);
  r[4] = f2b(b.x); r[5] = f2b(b.y); r[6] = f2b(b.z); r[7] = f2b(b.w);
  return r;
}

// ---------------------------------------------------------------------------
// K1: blocks [0,128): enc1 (K=512) + LN + relu -> enc2 (K=256) -> mf bf16.
//     blocks [128,288): convert in_proj_w + con_w1(repacked) to bf16 (wbf)
//     — runs concurrently with enc blocks, no extra launch.
// ---------------------------------------------------------------------------
__global__ __launch_bounds__(512) void k_enc(
    const float* __restrict__ me,
    const float* __restrict__ w1f, const float* __restrict__ b1,
    const float* __restrict__ g, const float* __restrict__ lb,
    const float* __restrict__ w2f, const float* __restrict__ b2,
    const float* __restrict__ in_proj_w, const float* __restrict__ con_w1,
    unsigned short* __restrict__ mfb, unsigned short* __restrict__ wbf,
    float* __restrict__ poolctx) {
  __shared__ float hh[16 * 260];
  __shared__ unsigned short rA[16 * 264];
  __shared__ unsigned short mfs[16 * 256];
  int tid = threadIdx.x;
  if (blockIdx.x >= 128) {
    // weight conversion: 160 blocks x 512 threads x 4 elems = 327680
    int base = ((blockIdx.x - 128) * 512 + tid) * 4;
#pragma unroll
    for (int u = 0; u < 4; ++u) {
      int idx = base + u;
      float v;
      if (idx < 196608) v = in_proj_w[idx];
      else {
        int i = idx - 196608, n = i >> 8, k = i & 255;
        v = (n < 256) ? con_w1[n * 512 + k] : con_w1[(n - 256) * 512 + 256 + k];
      }
      wbf[idx] = (unsigned short)f2b(v);
    }
    return;
  }
  int lane = tid & 63, w = tid >> 6;
  int row0 = blockIdx.x * 16;
  int m = lane & 15, q = lane >> 4;
  if (blockIdx.x == 0) {
    float4 z = {0.f, 0.f, 0.f, 0.f};
    ((float4*)poolctx)[tid] = z;
  }
  {
    f32x4 acc0 = (f32x4){0.f, 0.f, 0.f, 0.f};
    f32x4 acc1 = (f32x4){0.f, 0.f, 0.f, 0.f};
    const float* ap = me + (size_t)(row0 + m) * 512 + q * 8;
    const float* bp0 = w1f + (size_t)(w * 32 + m) * 512 + q * 8;
    const float* bp1 = w1f + (size_t)(w * 32 + 16 + m) * 512 + q * 8;
    float4 pa[4][2], pb[4][2][2];
#pragma unroll
    for (int d = 0; d < 4; ++d) {
      pa[d][0] = *(const float4*)(ap + d * 32);
      pa[d][1] = *(const float4*)(ap + d * 32 + 4);
      pb[d][0][0] = *(const float4*)(bp0 + d * 32);
      pb[d][0][1] = *(const float4*)(bp0 + d * 32 + 4);
      pb[d][1][0] = *(const float4*)(bp1 + d * 32);
      pb[d][1][1] = *(const float4*)(bp1 + d * 32 + 4);
    }
#pragma unroll
    for (int it = 0; it < 16; ++it) {
      int slot = it & 3;
      float4 a0 = pa[slot][0], a1 = pa[slot][1];
      float4 b00 = pb[slot][0][0], b01 = pb[slot][0][1];
      float4 b10 = pb[slot][1][0], b11 = pb[slot][1][1];
      if (it + 4 < 16) {
        pa[slot][0] = *(const float4*)(ap + (it + 4) * 32);
        pa[slot][1] = *(const float4*)(ap + (it + 4) * 32 + 4);
        pb[slot][0][0] = *(const float4*)(bp0 + (it + 4) * 32);
        pb[slot][0][1] = *(const float4*)(bp0 + (it + 4) * 32 + 4);
        pb[slot][1][0] = *(const float4*)(bp1 + (it + 4) * 32);
        pb[slot][1][1] = *(const float4*)(bp1 + (it + 4) * 32 + 4);
      }
      bf16x8 af = cvt8(a0, a1);
      acc0 = __builtin_amdgcn_mfma_f32_16x16x32_bf16(af, cvt8(b00, b01), acc0, 0, 0, 0);
      acc1 = __builtin_amdgcn_mfma_f32_16x16x32_bf16(af, cvt8(b10, b11), acc1, 0, 0, 0);
    }
#pragma unroll
    for (int nt = 0; nt < 2; ++nt) {
      int col = w * 32 + nt * 16 + m;
      float bias = b1[col];
      f32x4 a = nt ? acc1 : acc0;
#pragma unroll
      for (int reg = 0; reg < 4; ++reg)
        hh[(q * 4 + reg) * 260 + col] = a[reg] + bias;
    }
  }
  __syncthreads();
  {
    float4 g4 = *(const float4*)(g + lane * 4);
    float4 lb4 = *(const float4*)(lb + lane * 4);
#pragma unroll
    for (int rr = 0; rr < 2; ++rr) {
      int r = w * 2 + rr;
      float4 v = *(const float4*)&hh[r * 260 + lane * 4];
      float s1 = v.x + v.y + v.z + v.w;
      float s2 = v.x * v.x + v.y * v.y + v.z * v.z + v.w * v.w;
#pragma unroll
      for (int o = 32; o > 0; o >>= 1) {
        s1 += __shfl_xor(s1, o, 64);
        s2 += __shfl_xor(s2, o, 64);
      }
      float mu = s1 * (1.f / 256.f);
      float var = s2 * (1.f / 256.f) - mu * mu;
      float rs = rsqrtf(var + 1e-5f);
      unsigned short y0 = (unsigned short)f2b(fmaxf((v.x - mu) * rs * g4.x + lb4.x, 0.f));
      unsigned short y1 = (unsigned short)f2b(fmaxf((v.y - mu) * rs * g4.y + lb4.y, 0.f));
      unsigned short y2 = (unsigned short)f2b(fmaxf((v.z - mu) * rs * g4.z + lb4.z, 0.f));
      unsigned short y3 = (unsigned short)f2b(fmaxf((v.w - mu) * rs * g4.w + lb4.w, 0.f));
      uint2 pk;
      pk.x = (unsigned)y0 | ((unsigned)y1 << 16);
      pk.y = (unsigned)y2 | ((unsigned)y3 << 16);
      *(uint2*)&rA[r * 264 + lane * 4] = pk;
    }
  }
  __syncthreads();
  {
    f32x4 acc0 = (f32x4){0.f, 0.f, 0.f, 0.f};
    f32x4 acc1 = (f32x4){0.f, 0.f, 0.f, 0.f};
    const float* cp0 = w2f + (size_t)(w * 32 + m) * 256 + q * 8;
    const float* cp1 = w2f + (size_t)(w * 32 + 16 + m) * 256 + q * 8;
    float4 pb[4][2][2];
#pragma unroll
    for (int d = 0; d < 4; ++d) {
      pb[d][0][0] = *(const float4*)(cp0 + d * 32);
      pb[d][0][1] = *(const float4*)(cp0 + d * 32 + 4);
      pb[d][1][0] = *(const float4*)(cp1 + d * 32);
      pb[d][1][1] = *(const float4*)(cp1 + d * 32 + 4);
    }
#pragma unroll
    for (int it = 0; it < 8; ++it) {
      int slot = it & 3;
      float4 b00 = pb[slot][0][0], b01 = pb[slot][0][1];
      float4 b10 = pb[slot][1][0], b11 = pb[slot][1][1];
      if (it + 4 < 8) {
        pb[slot][0][0] = *(const float4*)(cp0 + (it + 4) * 32);
        pb[slot][0][1] = *(const float4*)(cp0 + (it + 4) * 32 + 4);
        pb[slot][1][0] = *(const float4*)(cp1 + (it + 4) * 32);
        pb[slot][1][1] = *(const float4*)(cp1 + (it + 4) * 32 + 4);
      }
      bf16x8 af = *(const bf16x8*)&rA[m * 264 + it * 32 + q * 8];
      acc0 = __builtin_amdgcn_mfma_f32_16x16x32_bf16(af, cvt8(b00, b01), acc0, 0, 0, 0);
      acc1 = __builtin_amdgcn_mfma_f32_16x16x32_bf16(af, cvt8(b10, b11), acc1, 0, 0, 0);
    }
#pragma unroll
    for (int nt = 0; nt < 2; ++nt) {
      int col = w * 32 + nt * 16 + m;
      float bias = b2[col];
      f32x4 a = nt ? acc1 : acc0;
#pragma unroll
      for (int reg = 0; reg < 4; ++reg)
        mfs[(q * 4 + reg) * 256 + col] = (unsigned short)f2b(a[reg] + bias);
    }
  }
  __syncthreads();
  {
    const uint4* src = (const uint4*)mfs;
    uint4* dst = (uint4*)(mfb + (size_t)row0 * 256);
    dst[tid] = src[tid];
  }
}

// ---------------------------------------------------------------------------
// K2: five 2048x256x256 GEMMs — bf16 weights (wbf). q/k/v written HEAD-MAJOR
// [b][h][s][32]; a/b row-major as before.
// ---------------------------------------------------------------------------
__global__ __launch_bounds__(256) void k_proj5(
    const unsigned short* __restrict__ mfb,
    const unsigned short* __restrict__ wbf,
    const float* __restrict__ bq, const float* __restrict__ cb1,
    float* __restrict__ qh, float* __restrict__ kh, float* __restrict__ vh,
    float* __restrict__ amat, float* __restrict__ bmat) {
  int tid = threadIdx.x, lane = tid & 63, w = tid >> 6;
  int row0 = blockIdx.x * 16;
  int part = blockIdx.y;
  int m = lane & 15, q = lane >> 4;
  const unsigned short* W = wbf + (size_t)part * 65536;
  bf16x8 a[8];
#pragma unroll
  for (int ks = 0; ks < 8; ++ks)
    a[ks] = *(const bf16x8*)(mfb + (size_t)(row0 + m) * 256 + ks * 32 + q * 8);
  f32x4 acc[4];
#pragma unroll
  for (int i = 0; i < 4; ++i) acc[i] = (f32x4){0.f, 0.f, 0.f, 0.f};
  bf16x8 pb[4][4];
#pragma unroll
  for (int d = 0; d < 4; ++d)
#pragma unroll
    for (int nt = 0; nt < 4; ++nt)
      pb[d][nt] = *(const bf16x8*)(W + (size_t)(w * 64 + nt * 16 + m) * 256 + d * 32 + q * 8);
#pragma unroll
  for (int it = 0; it < 8; ++it) {
    int slot = it & 3;
    bf16x8 bl0 = pb[slot][0], bl1 = pb[slot][1];
    bf16x8 bl2 = pb[slot][2], bl3 = pb[slot][3];
    if (it + 4 < 8) {
#pragma unroll
      for (int nt = 0; nt < 4; ++nt)
        pb[slot][nt] = *(const bf16x8*)(W + (size_t)(w * 64 + nt * 16 + m) * 256 + (it + 4) * 32 + q * 8);
    }
    acc[0] = __builtin_amdgcn_mfma_f32_16x16x32_bf16(a[it], bl0, acc[0], 0, 0, 0);
    acc[1] = __builtin_amdgcn_mfma_f32_16x16x32_bf16(a[it], bl1, acc[1], 0, 0, 0);
    acc[2] = __builtin_amdgcn_mfma_f32_16x16x32_bf16(a[it], bl2, acc[2], 0, 0, 0);
    acc[3] = __builtin_amdgcn_mfma_f32_16x16x32_bf16(a[it], bl3, acc[3], 0, 0, 0);
  }
#pragma unroll
  for (int nt = 0; nt < 4; ++nt) {
    int col = w * 64 + nt * 16 + m;
    if (part < 3) {
      float bias = bq[part * 256 + col];
      float* dst = (part == 0) ? qh : (part == 1) ? kh : vh;
      int h = col >> 5, d = col & 31;
#pragma unroll
      for (int reg = 0; reg < 4; ++reg) {
        int row = row0 + q * 4 + reg;
        int b = row >> 8, s = row & 255;
        dst[(((size_t)(b * 8 + h)) * 256 + s) * 32 + d] = acc[nt][reg] + bias;
      }
    } else {
      float bias = (part == 3) ? cb1[col] : 0.f;
      float* dst = (part == 3) ? amat : bmat;
#pragma unroll
      for (int reg = 0; reg < 4; ++reg) {
        int row = row0 + q * 4 + reg;
        dst[(size_t)row * 256 + col] = acc[nt][reg] + bias;
      }
    }
  }
}

// ---------------------------------------------------------------------------
// ATTN v4: head-major Q/K/V -> fully coalesced staging; QK^T MFMA ->
// in-register softmax -> PV MFMA + attnb write + pooled atomics.
// grid = (b,h,sg) = 512 blocks.
// ---------------------------------------------------------------------------
__global__ __launch_bounds__(256) void k_attn_mfma(
    const float* __restrict__ qh, const float* __restrict__ kh,
    const float* __restrict__ vh, unsigned short* __restrict__ attnb,
    float* __restrict__ poolctx) {
  __shared__ unsigned short qs[32 * 40];
  __shared__ unsigned short kb[256 * 40];
  __shared__ unsigned short vt[32 * 264];
  __shared__ unsigned short ps[32 * 264];
  __shared__ float redm[2][32];
  __shared__ float reds[2][32];
  int blk = blockIdx.x;
  int sg = blk & 7, bh = blk >> 3, h = bh & 7, b = bh >> 3;
  int tid = threadIdx.x, lane = tid & 63, w = tid >> 6;
  int m = lane & 15, q = lane >> 4;
  // stage Q (contiguous 4 KB: one float4 per thread)
  {
    const float* qbase = qh + (((size_t)bh) * 256 + sg * 32) * 32;
    float4 v = ((const float4*)qbase)[tid];
    int r = tid >> 3, c4 = tid & 7;
    unsigned short* dst = &qs[r * 40 + c4 * 4];
    dst[0] = (unsigned short)f2b(v.x); dst[1] = (unsigned short)f2b(v.y);
    dst[2] = (unsigned short)f2b(v.z); dst[3] = (unsigned short)f2b(v.w);
  }
  // stage K (contiguous 32 KB: 8 float4 per thread)
  {
    const float4* kbase = (const float4*)(kh + ((size_t)bh) * 256 * 32);
#pragma unroll
    for (int i = 0; i < 8; ++i) {
      int f = i * 256 + tid;
      float4 v = kbase[f];
      int r = f >> 3, c4 = f & 7;
      unsigned short* dst = &kb[r * 40 + c4 * 4];
      dst[0] = (unsigned short)f2b(v.x); dst[1] = (unsigned short)f2b(v.y);
      dst[2] = (unsigned short)f2b(v.z); dst[3] = (unsigned short)f2b(v.w);
    }
  }
  // stage V^T (lane = t; rows now only 128B apart)
  {
    const float4* vr = (const float4*)(vh + (((size_t)bh) * 256 + tid) * 32);
#pragma unroll
    for (int d4 = 0; d4 < 8; ++d4) {
      float4 vv = vr[d4];
      vt[(d4 * 4 + 0) * 264 + tid] = (unsigned short)f2b(vv.x);
      vt[(d4 * 4 + 1) * 264 + tid] = (unsigned short)f2b(vv.y);
      vt[(d4 * 4 + 2) * 264 + tid] = (unsigned short)f2b(vv.z);
      vt[(d4 * 4 + 3) * 264 + tid] = (unsigned short)f2b(vv.w);
    }
  }
  __syncthreads();
  int mt = w & 1, ng = w >> 1;
  int lrow = mt * 16 + q * 4;
  f32x4 acc[8];
  {
    bf16x8 af = *(const bf16x8*)&qs[(mt * 16 + m) * 40 + q * 8];
#pragma unroll
    for (int nt = 0; nt < 8; ++nt) {
      bf16x8 bf = *(const bf16x8*)&kb[(ng * 128 + nt * 16 + m) * 40 + q * 8];
      acc[nt] = __builtin_amdgcn_mfma_f32_16x16x32_bf16(
          af, bf, (f32x4){0.f, 0.f, 0.f, 0.f}, 0, 0, 0);
    }
  }
  const float scale = 0.17677669529663689f;
#pragma unroll
  for (int nt = 0; nt < 8; ++nt)
#pragma unroll
    for (int reg = 0; reg < 4; ++reg) acc[nt][reg] *= scale;
  float pm[4];
#pragma unroll
  for (int reg = 0; reg < 4; ++reg) {
    float mx = acc[0][reg];
#pragma unroll
    for (int nt = 1; nt < 8; ++nt) mx = fmaxf(mx, acc[nt][reg]);
#pragma unroll
    for (int o = 1; o < 16; o <<= 1) mx = fmaxf(mx, __shfl_xor(mx, o, 64));
    pm[reg] = mx;
  }
  if (m == 0) {
#pragma unroll
    for (int reg = 0; reg < 4; ++reg) redm[ng][lrow + reg] = pm[reg];
  }
  __syncthreads();
  float inv[4];
  float psum[4];
#pragma unroll
  for (int reg = 0; reg < 4; ++reg) {
    float Mv = fmaxf(redm[0][lrow + reg], redm[1][lrow + reg]);
    float s = 0.f;
#pragma unroll
    for (int nt = 0; nt < 8; ++nt) {
      float e = __expf(acc[nt][reg] - Mv);
      acc[nt][reg] = e;
      s += e;
    }
#pragma unroll
    for (int o = 1; o < 16; o <<= 1) s += __shfl_xor(s, o, 64);
    psum[reg] = s;
  }
  if (m == 0) {
#pragma unroll
    for (int reg = 0; reg < 4; ++reg) reds[ng][lrow + reg] = psum[reg];
  }
  __syncthreads();
#pragma unroll
  for (int reg = 0; reg < 4; ++reg)
    inv[reg] = 1.f / (reds[0][lrow + reg] + reds[1][lrow + reg]);
#pragma unroll
  for (int nt = 0; nt < 8; ++nt) {
    int t = ng * 128 + nt * 16 + m;
#pragma unroll
    for (int reg = 0; reg < 4; ++reg)
      ps[(lrow + reg) * 264 + t] = (unsigned short)f2b(acc[nt][reg] * inv[reg]);
  }
  __syncthreads();
  {
    int r = tid >> 3, seg = tid & 7;
    const uint4* src = (const uint4*)&ps[r * 264 + seg * 32];
    uint4* dst = (uint4*)(attnb + ((size_t)(bh * 256 + sg * 32 + r)) * 256 + seg * 32);
    dst[0] = src[0]; dst[1] = src[1]; dst[2] = src[2]; dst[3] = src[3];
  }
  {
    int dt = w >> 1;
    f32x4 a = (f32x4){0.f, 0.f, 0.f, 0.f};
#pragma unroll
    for (int ks = 0; ks < 256; ks += 32) {
      bf16x8 af = *(const bf16x8*)&ps[(mt * 16 + m) * 264 + ks + q * 8];
      bf16x8 bf = *(const bf16x8*)&vt[(dt * 16 + m) * 264 + ks + q * 8];
      a = __builtin_amdgcn_mfma_f32_16x16x32_bf16(af, bf, a, 0, 0, 0);
    }
    float colsum = a[0] + a[1] + a[2] + a[3];
    colsum += __shfl_xor(colsum, 16, 64);
    colsum += __shfl_xor(colsum, 32, 64);
    if (lane < 16)
      atomicAdd(&poolctx[b * 256 + h * 32 + dt * 16 + m], colsum);
  }
}

// ---------------------------------------------------------------------------
// TAIL: blocks [0,288) pair scores; [288,544) attn mean; [544,552) heads.
// ---------------------------------------------------------------------------
__global__ __launch_bounds__(256) void k_tail(
    const float* __restrict__ amat, const float* __restrict__ bmat,
    const float* __restrict__ conw2, const float* __restrict__ conb2,
    float* __restrict__ M,
    const unsigned short* __restrict__ attnb, float* __restrict__ out_aw,
    const float* __restrict__ poolctx,
    const float* __restrict__ outw, const float* __restrict__ outb,
    const float* __restrict__ cw1, const float* __restrict__ cb1h,
    const float* __restrict__ cw2, const float* __restrict__ cb2,
    const float* __restrict__ hw1, const float* __restrict__ hb1,
    const float* __restrict__ hw2, const float* __restrict__ hb2,
    float* __restrict__ out) {
  __shared__ float smem[32 * 132 * 2 + 256];
  int bx = blockIdx.x, tid = threadIdx.x;
  if (bx < 288) {
    float* As = smem;
    float* Bs = smem + 32 * 132;
    float* w2s = smem + 32 * 132 * 2;
    int b = bx / 36, tix = bx % 36;
    int it = 0, rem = tix;
    while (rem >= 8 - it) { rem -= 8 - it; ++it; }
    int jt = it + rem;
    int tj = tid & 15, ti = tid >> 4;
    w2s[tid] = conw2[tid];
    float acc00 = 0, acc01 = 0, acc10 = 0, acc11 = 0;
    const float* Ab = amat + ((size_t)(b * 256 + it * 32)) * 256;
    const float* Bb = bmat + ((size_t)(b * 256 + jt * 32)) * 256;
    for (int ch = 0; ch < 2; ++ch) {
      __syncthreads();
#pragma unroll
      for (int k = 0; k < 4; ++k) {
        int f = tid + k * 256;
        int r = f >> 5, c4 = f & 31;
        float4 va = *(const float4*)(Ab + (size_t)r * 256 + ch * 128 + c4 * 4);
        float4 vb = *(const float4*)(Bb + (size_t)r * 256 + ch * 128 + c4 * 4);
        *(float4*)&As[r * 132 + c4 * 4] = va;
        *(float4*)&Bs[r * 132 + c4 * 4] = vb;
      }
      __syncthreads();
      const float* a0 = As + (2 * ti) * 132;
      const float* a1 = a0 + 132;
      const float* b0 = Bs + (2 * tj) * 132;
      const float* b1 = b0 + 132;
      const float* w2c = w2s + ch * 128;
      for (int d = 0; d < 128; d += 4) {
        float4 wv = *(const float4*)&w2c[d];
        float4 av0 = *(const float4*)&a0[d];
        float4 av1 = *(const float4*)&a1[d];
        float4 bv0 = *(const float4*)&b0[d];
        float4 bv1 = *(const float4*)&b1[d];
        acc00 += fmaxf(av0.x + bv0.x, 0.f) * wv.x + fmaxf(av0.y + bv0.y, 0.f) * wv.y
               + fmaxf(av0.z + bv0.z, 0.f) * wv.z + fmaxf(av0.w + bv0.w, 0.f) * wv.w;
        acc01 += fmaxf(av0.x + bv1.x, 0.f) * wv.x + fmaxf(av0.y + bv1.y, 0.f) * wv.y
               + fmaxf(av0.z + bv1.z, 0.f) * wv.z + fmaxf(av0.w + bv1.w, 0.f) * wv.w;
        acc10 += fmaxf(av1.x + bv0.x, 0.f) * wv.x + fmaxf(av1.y + bv0.y, 0.f) * wv.y
               + fmaxf(av1.z + bv0.z, 0.f) * wv.z + fmaxf(av1.w + bv0.w, 0.f) * wv.w;
        acc11 += fmaxf(av1.x + bv1.x, 0.f) * wv.x + fmaxf(av1.y + bv1.y, 0.f) * wv.y
               + fmaxf(av1.z + bv1.z, 0.f) * wv.z + fmaxf(av1.w + bv1.w, 0.f) * wv.w;
      }
    }
    float c2 = conb2[0];
    float s00 = 1.f / (1.f + expf(-(acc00 + c2)));
    float s01 = 1.f / (1.f + expf(-(acc01 + c2)));
    float s10 = 1.f / (1.f + expf(-(acc10 + c2)));
    float s11 = 1.f / (1.f + expf(-(acc11 + c2)));
    float* Mb = M + ((size_t)b << 16);
    int i0 = it * 32 + 2 * ti, i1 = i0 + 1;
    int j0 = jt * 32 + 2 * tj, j1 = j0 + 1;
    if (it != jt) {
      Mb[i0 * 256 + j0] = s00; Mb[j0 * 256 + i0] = s00;
      Mb[i0 * 256 + j1] = s01; Mb[j1 * 256 + i0] = s01;
      Mb[i1 * 256 + j0] = s10; Mb[j0 * 256 + i1] = s10;
      Mb[i1 * 256 + j1] = s11; Mb[j1 * 256 + i1] = s11;
    } else {
      if (j0 > i0) { Mb[i0 * 256 + j0] = s00; Mb[j0 * 256 + i0] = s00; }
      else if (j0 == i0) Mb[i0 * 256 + j0] = 0.f;
      if (j1 > i0) { Mb[i0 * 256 + j1] = s01; Mb[j1 * 256 + i0] = s01; }
      if (j0 > i1) { Mb[i1 * 256 + j0] = s10; Mb[j0 * 256 + i1] = s10; }
      if (j1 > i1) { Mb[i1 * 256 + j1] = s11; Mb[j1 * 256 + i1] = s11; }
      else if (j1 == i1) Mb[i1 * 256 + j1] = 0.f;
    }
  } else if (bx < 544) {
    int gid = (bx - 288) * 256 + tid;
    int b = gid >> 13, e8 = gid & 8191;
    size_t e = (size_t)e8 * 8;
    float s0 = 0, s1 = 0, s2 = 0, s3 = 0, s4 = 0, s5 = 0, s6 = 0, s7 = 0;
#pragma unroll
    for (int h = 0; h < 8; ++h) {
      uint4 v = *(const uint4*)(attnb + (((size_t)(b * 8 + h)) << 16) + e);
      s0 += __uint_as_float(v.x << 16); s1 += __uint_as_float(v.x & 0xffff0000u);
      s2 += __uint_as_float(v.y << 16); s3 += __uint_as_float(v.y & 0xffff0000u);
      s4 += __uint_as_float(v.z << 16); s5 += __uint_as_float(v.z & 0xffff0000u);
      s6 += __uint_as_float(v.w << 16); s7 += __uint_as_float(v.w & 0xffff0000u);
    }
    float* dst = out_aw + ((size_t)b << 16) + e;
    float4 r0 = {s0 * 0.125f, s1 * 0.125f, s2 * 0.125f, s3 * 0.125f};
    float4 r1 = {s4 * 0.125f, s5 * 0.125f, s6 * 0.125f, s7 * 0.125f};
    *(float4*)dst = r0;
    *(float4*)(dst + 4) = r1;
  } else {
    float* pc = smem;
    float* psh = smem + 256;
    float* red = smem + 512;
    int b = bx - 544, j = tid;
    pc[j] = poolctx[b * 256 + j] * (1.f / 256.f);
    __syncthreads();
    float s = outb[j];
    const float4* wr = (const float4*)(outw + (size_t)j * 256);
    for (int k4 = 0; k4 < 64; ++k4) {
      float4 wv = wr[k4];
      const float* p = pc + k4 * 4;
      s += p[0] * wv.x + p[1] * wv.y + p[2] * wv.z + p[3] * wv.w;
    }
    psh[j] = s;
    __syncthreads();
    int jj = j & 127;
    bool isH = j >= 128;
    const float* w1 = isH ? hw1 : cw1;
    const float* bb1 = isH ? hb1 : cb1h;
    const float* w2 = isH ? hw2 : cw2;
    float a = bb1[jj];
    const float4* w1r = (const float4*)(w1 + (size_t)jj * 256);
    for (int k4 = 0; k4 < 64; ++k4) {
      float4 wv = w1r[k4];
      const float* p = psh + k4 * 4;
      a += p[0] * wv.x + p[1] * wv.y + p[2] * wv.z + p[3] * wv.w;
    }
    float v = fmaxf(a, 0.f) * w2[jj];
#pragma unroll
    for (int o = 32; o > 0; o >>= 1) v += __shfl_xor(v, o, 64);
    if ((j & 63) == 0) red[j >> 6] = v;
    __syncthreads();
    if (j == 0) {
      float c = red[0] + red[1] + cb2[0];
      float h = red[2] + red[3] + hb2[0];
      out[b] = 1.f / (1.f + expf(-c));
      out[8 + b] = 1.f / (1.f + expf(-h));
    }
  }
}

// ---------------------------------------------------------------------------
extern "C" void kernel_launch(void* const* d_in, const int* in_sizes, int n_in,
                              void* d_out, int out_size, void* d_ws, size_t ws_size,
                              hipStream_t stream) {
  const float* me        = (const float*)d_in[0];
  const float* enc_w1    = (const float*)d_in[1];
  const float* enc_b1    = (const float*)d_in[2];
  const float* ln_g      = (const float*)d_in[3];
  const float* ln_b      = (const float*)d_in[4];
  const float* enc_w2    = (const float*)d_in[5];
  const float* enc_b2    = (const float*)d_in[6];
  const float* in_proj_w = (const float*)d_in[7];
  const float* in_proj_b = (const float*)d_in[8];
  const float* out_w     = (const float*)d_in[9];
  const float* out_b     = (const float*)d_in[10];
  const float* cons_w1   = (const float*)d_in[11];
  const float* cons_b1   = (const float*)d_in[12];
  const float* cons_w2   = (const float*)d_in[13];
  const float* cons_b2   = (const float*)d_in[14];
  const float* hall_w1   = (const float*)d_in[15];
  const float* hall_b1   = (const float*)d_in[16];
  const float* hall_w2   = (const float*)d_in[17];
  const float* hall_b2   = (const float*)d_in[18];
  const float* con_w1    = (const float*)d_in[19];
  const float* con_b1    = (const float*)d_in[20];
  const float* con_w2    = (const float*)d_in[21];
  const float* con_b2    = (const float*)d_in[22];

  // workspace layout (float offsets)
  float* ws = (float*)d_ws;
  float* qh   = ws;                                        // [0, 524288)
  float* kh   = ws + 524288;                               // [524288, 1048576)
  float* vh   = ws + 1048576;                              // [1048576, 1572864)
  unsigned short* attnb = (unsigned short*)(ws + 1572864); // [1572864, 3670016)
  float* amat = ws + 3670016;                              // [3670016, 4194304)
  float* bmat = ws + 4194304;                              // [4194304, 4718592)
  unsigned short* mfb = (unsigned short*)(ws + 4718592);   // [4718592, 4980736)
  unsigned short* wbf = (unsigned short*)(ws + 4980736);   // 327680 us -> [4980736, 5144576)
  float* poolctx = ws + 5144576;                           // [5144576, 5146624)

  float* out    = (float*)d_out;
  float* out_M  = out + 16;
  float* out_aw = out + 16 + 524288;

  k_enc<<<288, 512, 0, stream>>>(me, enc_w1, enc_b1, ln_g, ln_b,
                                 enc_w2, enc_b2, in_proj_w, con_w1,
                                 mfb, wbf, poolctx);
  k_proj5<<<dim3(128, 5), 256, 0, stream>>>(mfb, wbf, in_proj_b, con_b1,
                                            qh, kh, vh, amat, bmat);
  k_attn_mfma<<<512, 256, 0, stream>>>(qh, kh, vh, attnb, poolctx);
  k_tail<<<552, 256, 0, stream>>>(amat, bmat, con_w2, con_b2, out_M,
                                  attnb, out_aw, poolctx,
                                  out_w, out_b,
                                  cons_w1, cons_b1, cons_w2, cons_b2,
                                  hall_w1, hall_b1, hall_w2, hall_b2, out);
}